// Round 6
// baseline (583.595 us; speedup 1.0000x reference)
//
#include <hip/hip_runtime.h>
#include <hip/hip_bf16.h>

#define B_ 4
#define T_ 2048
#define C_ 1024
#define NH_ 16
#define FF_ 4096
#define NT_ (B_*T_)   // 8192 token rows

typedef short bf16x8 __attribute__((ext_vector_type(8)));
typedef float f32x4 __attribute__((ext_vector_type(4)));

#define LDS_AS(p) ((__attribute__((address_space(3))) uint32_t*)(p))
#define GLB_AS(p) ((const __attribute__((address_space(1))) uint32_t*)(p))

__device__ __forceinline__ float bf2f(__hip_bfloat16 v){ return __bfloat162float(v); }
__device__ __forceinline__ __hip_bfloat16 f2bf(float f){ return __float2bfloat16(f); }

__device__ __forceinline__ f32x4 mfma16(bf16x8 a, bf16x8 b, f32x4 c){
  return __builtin_amdgcn_mfma_f32_16x16x32_bf16(a, b, c, 0, 0, 0);
}

// inline-asm ds_read_b128 from a raw 32-bit LDS byte address + literal offset.
// OPAQUE to the compiler's waitcnt pass (no conservative vmcnt(0) LDS-DMA-alias
// drain). Caller must s_waitcnt lgkmcnt(0) + sched_barrier(0) before consuming.
#define DSR(dst_, addr_, off_) \
  asm volatile("ds_read_b128 %0, %1 offset:" #off_ : "=v"(dst_) : "v"(addr_))

// ---------------- weight transpose + fp32->bf16 cast:  in[K][N] -> out[N][K] ----------------
__global__ __launch_bounds__(256) void transpose_bf16(const float* __restrict__ in,
                                                      __hip_bfloat16* __restrict__ out,
                                                      int K, int N) {
  __shared__ float tile[32][33];
  const int n0 = blockIdx.x * 32, k0 = blockIdx.y * 32;
  const int x = threadIdx.x & 31, y = threadIdx.x >> 5;   // y in 0..7
  #pragma unroll
  for (int i = 0; i < 4; i++)
    tile[y + 8*i][x] = in[(size_t)(k0 + y + 8*i) * N + n0 + x];
  __syncthreads();
  #pragma unroll
  for (int i = 0; i < 4; i++)
    out[(size_t)(n0 + y + 8*i) * K + k0 + x] = f2bf(tile[x][y + 8*i]);
}

// ---------------- LayerNorm fp32 -> bf16 (row = 1024) ----------------
__global__ __launch_bounds__(256) void ln_bf16(const float* __restrict__ x,
                                               const float* __restrict__ g,
                                               const float* __restrict__ b,
                                               __hip_bfloat16* __restrict__ out) {
  const int row = blockIdx.x;
  const int tid = threadIdx.x;
  float4 v = ((const float4*)(x + (size_t)row * C_))[tid];
  float s  = v.x + v.y + v.z + v.w;
  float s2 = v.x*v.x + v.y*v.y + v.z*v.z + v.w*v.w;
  #pragma unroll
  for (int off = 32; off > 0; off >>= 1) {
    s  += __shfl_down(s,  off, 64);
    s2 += __shfl_down(s2, off, 64);
  }
  __shared__ float red[8];
  const int w = tid >> 6, l = tid & 63;
  if (l == 0) { red[w] = s; red[4 + w] = s2; }
  __syncthreads();
  s  = red[0] + red[1] + red[2] + red[3];
  s2 = red[4] + red[5] + red[6] + red[7];
  const float mu   = s * (1.0f / C_);
  const float var  = s2 * (1.0f / C_) - mu * mu;
  const float rstd = rsqrtf(var + 1e-5f);
  float4 gv = ((const float4*)g)[tid];
  float4 bv = ((const float4*)b)[tid];
  ushort4 o;
  __hip_bfloat16 t;
  t = f2bf((v.x - mu) * rstd * gv.x + bv.x); o.x = *(unsigned short*)&t;
  t = f2bf((v.y - mu) * rstd * gv.y + bv.y); o.y = *(unsigned short*)&t;
  t = f2bf((v.z - mu) * rstd * gv.z + bv.z); o.z = *(unsigned short*)&t;
  t = f2bf((v.w - mu) * rstd * gv.w + bv.w); o.w = *(unsigned short*)&t;
  ((ushort4*)out)[(size_t)row * (C_/4) + tid] = o;
}

// ---------------- MFMA GEMM v6: 256x256 phase-structured (T2+T3+T4+T5) ----------------
// C[M][N] = A[M][K] * BT[N][K]^T + epilogue. BM=BN=256, BK=64, 8 waves (2m x 4n),
// per-wave out 128x64 (8 m-frags x 4 n-frags). LDS = 2 x (A 32KB + B 32KB) = 128KB.
// v5 post-mortem: 2-phase counted-vmcnt = 611 TF, exactly the regime-gate ceiling
// (m230/m248: 2ph ~655-682). The lever is the per-K-tile PHASE interleave (T3):
//   tile top:  STAGE whole next K-tile (8 gload_lds) -> s_waitcnt vmcnt(8) (counted,
//              never 0 in steady loop: next tile gets ~4 phases of flight) -> barrier
//   phase p (x4): 4 asm ds_read (A m-frags 2p,2p+1 x 2 k-halves)  [phase 0: + 8 B reads]
//              -> lgkmcnt(0) + sched_barrier(0) (rule 18) -> setprio(1) 16 MFMA
//              setprio(0) -> barrier
// B-frags read once (phase 0), held in regs (32 VGPR). K-loop unrolled x2 so the
// LDS buffer parity is compile-time. Hazards: buf b is overwritten by STAGE only
// after the previous tile-in-b's last phase barrier (all its ds_reads retired at
// lgkmcnt(0) before that barrier); per-wave vmcnt(8) precedes the shared barrier
// so the consumed tile is fully landed across waves.
// LDS addressing: row&7 == m_&7 for every fragment row -> XOR slot is a
// thread-constant; 4 precomputed u32 base addrs + literal offset:mi*2048.
// Staging: slot s of row r holds global 16B chunk s^(r&7) (same swizzle as v4/v5).
// 2D-chunked XCD swizzle: XCD owns CW n-tiles x RH m-tiles (B-set <= 3MB L2-resident).
// MODE 0: QKV. cols <2048 -> bf16 qk[row][col]; cols >=2048 -> bf16 vT[b,dg,t]
// MODE 1: out f32  = resid + C + bias    (proj)
// MODE 2: out bf16 = gelu(C + bias)      (FC)
// MODE 3: out f32  = resid + C + bias    (FC2)
template <int MODE>
__global__ __launch_bounds__(512, 1) void gemm8p(const __hip_bfloat16* __restrict__ A,
                                                 const __hip_bfloat16* __restrict__ BT,
                                                 const float* __restrict__ bias,
                                                 const float* __restrict__ resid,
                                                 void* __restrict__ outp,
                                                 void* __restrict__ outp2,
                                                 int N, int K, int CW) {
  __shared__ __hip_bfloat16 Als[2][256 * 64];   // 64KB  (buffer stride 32768 B)
  __shared__ __hip_bfloat16 Bls[2][256 * 64];   // 64KB
  const int tid = threadIdx.x;
  const int w = tid >> 6, l = tid & 63;
  const int wm = w >> 2, wn = w & 3;            // wave grid 2(m) x 4(n)
  const int m_ = l & 15, q_ = l >> 4;
  const int w8 = w << 3;                        // wave-uniform staging row base
  const int srow = tid >> 3;                    // 0..63 row within a 64-row slab
  const int schunk = (tid & 7) ^ (srow & 7);    // XOR-preswizzled global chunk

  // 2D-chunked XCD swizzle
  const int nbx = N >> 8;
  const int bid = blockIdx.x;
  const int x8 = bid & 7, i8 = bid >> 3;
  const int ccols = nbx / CW;
  const int RH = ((int)(gridDim.x >> 3)) / CW;
  const int tile_n = ((x8 % ccols) * CW + i8 % CW) << 8;
  const int tile_m = ((x8 / ccols) * RH + i8 / CW) << 8;

  f32x4 acc[8][4] = {};

  // staging pointers: 4 slabs of 64 rows each for A and B; advance 64 elems/tile
  const __hip_bfloat16* gpa[4];
  const __hip_bfloat16* gpb[4];
  #pragma unroll
  for (int i = 0; i < 4; i++) {
    gpa[i] = A  + (size_t)(tile_m + i*64 + srow) * K + schunk*8;
    gpb[i] = BT + (size_t)(tile_n + i*64 + srow) * K + schunk*8;
  }

#define STAGE_T(buf_) do {                                                        \
    _Pragma("unroll")                                                             \
    for (int i = 0; i < 4; i++) {                                                 \
      __builtin_amdgcn_global_load_lds(GLB_AS(gpa[i]),                            \
          LDS_AS(&Als[buf_][(i*64 + w8) * 64]), 16, 0, 0);                        \
      gpa[i] += 64;                                                               \
      __builtin_amdgcn_global_load_lds(GLB_AS(gpb[i]),                            \
          LDS_AS(&Bls[buf_][(i*64 + w8) * 64]), 16, 0, 0);                        \
      gpb[i] += 64;                                                               \
    }                                                                             \
  } while (0)

  // LDS read bases (u32 byte addrs). row&7 == m_&7 for all frag rows.
  const uint32_t ab = (uint32_t)(uintptr_t)LDS_AS(&Als[0][0]);
  const uint32_t bb = (uint32_t)(uintptr_t)LDS_AS(&Bls[0][0]);
  const uint32_t s0 = (uint32_t)(((q_)     ^ (m_ & 7)) * 16);
  const uint32_t s1 = (uint32_t)(((4 + q_) ^ (m_ & 7)) * 16);
  const uint32_t a_rd0 = ab + (uint32_t)((wm*128 + m_) * 128) + s0;
  const uint32_t a_rd1 = ab + (uint32_t)((wm*128 + m_) * 128) + s1;
  const uint32_t b_rd0 = bb + (uint32_t)((wn*64  + m_) * 128) + s0;
  const uint32_t b_rd1 = bb + (uint32_t)((wn*64  + m_) * 128) + s1;

#define PHASE(AOFF0, AOFF1, MI0, MI1) do {                                        \
    bf16x8 a00, a01, a10, a11;                                                    \
    DSR(a00, aa0, AOFF0); DSR(a01, aa1, AOFF0);                                   \
    DSR(a10, aa0, AOFF1); DSR(a11, aa1, AOFF1);                                   \
    asm volatile("s_waitcnt lgkmcnt(0)" ::: "memory");                            \
    __builtin_amdgcn_sched_barrier(0);                                            \
    __builtin_amdgcn_s_setprio(1);                                                \
    _Pragma("unroll")                                                             \
    for (int ni = 0; ni < 4; ni++) {                                              \
      acc[MI0][ni] = mfma16(a00, bfr[0][ni], acc[MI0][ni]);                       \
      acc[MI0][ni] = mfma16(a01, bfr[1][ni], acc[MI0][ni]);                       \
      acc[MI1][ni] = mfma16(a10, bfr[0][ni], acc[MI1][ni]);                       \
      acc[MI1][ni] = mfma16(a11, bfr[1][ni], acc[MI1][ni]);                       \
    }                                                                             \
    __builtin_amdgcn_s_setprio(0);                                                \
    __builtin_amdgcn_s_barrier();                                                 \
  } while (0)

#define KTILE(CL) do {                                                            \
    const uint32_t aa0 = a_rd0 + (CL)*32768u, aa1 = a_rd1 + (CL)*32768u;          \
    const uint32_t bb0 = b_rd0 + (CL)*32768u, bb1 = b_rd1 + (CL)*32768u;          \
    bf16x8 bfr[2][4];                                                             \
    DSR(bfr[0][0], bb0, 0);    DSR(bfr[0][1], bb0, 2048);                         \
    DSR(bfr[0][2], bb0, 4096); DSR(bfr[0][3], bb0, 6144);                         \
    DSR(bfr[1][0], bb1, 0);    DSR(bfr[1][1], bb1, 2048);                         \
    DSR(bfr[1][2], bb1, 4096); DSR(bfr[1][3], bb1, 6144);                         \
    PHASE(0,     2048,  0, 1);                                                    \
    PHASE(4096,  6144,  2, 3);                                                    \
    PHASE(8192,  10240, 4, 5);                                                    \
    PHASE(12288, 14336, 6, 7);                                                    \
  } while (0)

  const int nt = K >> 6;   // 16 or 64; always even
  STAGE_T(0);              // prologue: tile 0 in flight
  #pragma unroll 1
  for (int t = 0; t < nt; t += 2) {
    // ---- K-tile t (buf 0); stage tile t+1 (always exists: t <= nt-2) ----
    STAGE_T(1);
    asm volatile("s_waitcnt vmcnt(8)" ::: "memory");   // tile t landed; t+1 in flight
    __builtin_amdgcn_s_barrier();
    KTILE(0);
    // ---- K-tile t+1 (buf 1); stage tile t+2 if it exists ----
    if (t + 2 < nt) {
      STAGE_T(0);
      asm volatile("s_waitcnt vmcnt(8)" ::: "memory");
    } else {
      asm volatile("s_waitcnt vmcnt(0)" ::: "memory");
    }
    __builtin_amdgcn_s_barrier();
    KTILE(1);
  }
#undef STAGE_T
#undef PHASE
#undef KTILE

  // epilogue: C/D layout col=lane&15, row=(lane>>4)*4+reg
  const int r0 = tile_m + wm * 128 + q_ * 4;
  const int c0 = tile_n + wn * 64 + m_;
  #pragma unroll
  for (int mi = 0; mi < 8; mi++) {
    #pragma unroll
    for (int r = 0; r < 4; r++) {
      const int row = r0 + mi * 16 + r;
      #pragma unroll
      for (int ni = 0; ni < 4; ni++) {
        const int col = c0 + ni * 16;
        float v = acc[mi][ni][r] + bias[col];
        if (MODE == 0) {
          if (tile_n < 2 * C_) {
            ((__hip_bfloat16*)outp)[(size_t)row * (2*C_) + col] = f2bf(v);
          } else {
            // vT[(b*1024 + dg)][t], dg = col-2048, b = row>>11, t = row&2047
            const int dg = col - 2 * C_;
            ((__hip_bfloat16*)outp2)[((size_t)((row >> 11) * 1024 + dg)) * T_ + (row & 2047)] = f2bf(v);
          }
        } else if (MODE == 1 || MODE == 3) {
          ((float*)outp)[(size_t)row * N + col] = resid[(size_t)row * N + col] + v;
        } else { // gelu
          const float u = 0.7978845608028654f * (v + 0.044715f * v * v * v);
          const float e = __expf(2.0f * u);
          ((__hip_bfloat16*)outp)[(size_t)row * N + col] = f2bf(v * (1.0f - 1.0f / (e + 1.0f)));
        }
      }
    }
  }
}

// ---------------- flash attention v8 (causal) ---------------- (unchanged)
// qk: [B*T][2C] bf16 (Q cols 0..1023, K cols 1024..2047); vT: [B*NH*64][T] bf16
__global__ __launch_bounds__(256, 4) void flash_attn(const __hip_bfloat16* __restrict__ qk,
                                                     const __hip_bfloat16* __restrict__ vT,
                                                     __hip_bfloat16* __restrict__ y) {
  const int id  = blockIdx.x;          // 0..1023
  const int xcd = id & 7;
  const int jj  = id >> 3;             // 0..127
  const int bh  = xcd * 8 + (jj >> 4); // 8 bh per XCD
  const int p   = jj & 15;             // pair: qt=p and qt=31-p (64-row q-tiles)
  const int b   = bh >> 4, h = bh & 15;
  const int tid = threadIdx.x, w = tid >> 6, l = tid & 63;
  const int m_ = l & 15, q_ = l >> 4;
  const int lrow8 = l >> 3;            // 0..7 row within 8-row staging group
  const int gchunk = (l & 7) ^ lrow8;  // global 16B chunk this lane fetches

  __shared__ __hip_bfloat16 Kls[2][64 * 64];  // 16KB double-buffered K tile
  __shared__ __hip_bfloat16 Vls[64 * 64];     // 8KB V tile
  __shared__ __hip_bfloat16 Pls[64 * 76];     // 9.5KB wave-local P bands

  const size_t kgbase = (size_t)b * T_ * (2*C_) + C_ + h*64;  // + t*(2C) + d
  const size_t vgbase = (size_t)bh * 64 * T_;                 // + d*T + t

#define STAGE_K(kt_, buf_) do {                                                        \
    _Pragma("unroll")                                                                  \
    for (int j2 = 0; j2 < 2; j2++) {                                                   \
      const int rg = j2*32 + w*8;                                                      \
      __builtin_amdgcn_global_load_lds(                                                \
        GLB_AS(qk + kgbase + (size_t)((kt_)*64 + rg + lrow8)*(2*C_) + gchunk*8),       \
        LDS_AS(&Kls[buf_][rg*64]), 16, 0, 0);                                          \
    }                                                                                  \
  } while (0)

#define STAGE_V(kt_) do {                                                              \
    _Pragma("unroll")                                                                  \
    for (int j2 = 0; j2 < 2; j2++) {                                                   \
      const int rg = j2*32 + w*8;                                                      \
      __builtin_amdgcn_global_load_lds(                                                \
        GLB_AS(vT + vgbase + (size_t)(rg + lrow8)*T_ + (kt_)*64 + gchunk*8),           \
        LDS_AS(&Vls[rg*64]), 16, 0, 0);                                                \
    }                                                                                  \
  } while (0)

  #pragma unroll 1
  for (int ui = 0; ui < 2; ui++) {
    const int qt = ui ? (31 - p) : p;
    const int q0 = qt * 64;

    // --- Q fragment (A layout): 16 rows/wave, scaled by 1/8*log2(e) ---
    bf16x8 aq[2];
    {
      const float qscale = 0.125f * 1.44269504088896f;
      const size_t qbase = ((size_t)b * T_ + q0 + w*16 + m_) * (2*C_) + h*64;
      #pragma unroll
      for (int kh = 0; kh < 2; kh++) {
        union { uint4 u; __hip_bfloat16 h8[8]; } t;
        t.u = *(const uint4*)&qk[qbase + kh*32 + q_*8];
        __hip_bfloat16 a[8];
        #pragma unroll
        for (int jx = 0; jx < 8; jx++) a[jx] = f2bf(bf2f(t.h8[jx]) * qscale);
        aq[kh] = *(const bf16x8*)a;
      }
    }

    f32x4 accO[4] = {};
    float lsum[4] = {0.f, 0.f, 0.f, 0.f};

    // prologue: stage K[0]
    STAGE_K(0, 0);
    asm volatile("s_waitcnt vmcnt(0)" ::: "memory");
    __builtin_amdgcn_s_barrier();

    int cur = 0;
    #pragma unroll 1
    for (int kt = 0; kt <= qt; kt++) {
      // issue V[kt] staging; latency hides under QK^T + softmax
      STAGE_V(kt);

      // --- QK^T from LDS (B-fragment reads, XOR-swizzled: conflict-free) ---
      f32x4 s[4];
      #pragma unroll
      for (int ni = 0; ni < 4; ni++) {
        const int row = ni*16 + m_;
        const bf16x8 bk0 = *(const bf16x8*)&Kls[cur][row*64 + ((q_     ^ (row & 7)) * 8)];
        const bf16x8 bk1 = *(const bf16x8*)&Kls[cur][row*64 + (((4+q_) ^ (row & 7)) * 8)];
        f32x4 z = {};
        z = mfma16(aq[0], bk0, z);
        s[ni] = mfma16(aq[1], bk1, z);
      }

      // issue next K tile; stays in flight across the counted-vmcnt barrier
      if (kt < qt) STAGE_K(kt + 1, cur ^ 1);

      // --- causal mask: only the diagonal tile ---
      if (kt == qt) {
        const int qrow = w*16 + q_*4;
        #pragma unroll
        for (int ni = 0; ni < 4; ni++) {
          const int kcol = ni*16 + m_;
          #pragma unroll
          for (int r = 0; r < 4; r++)
            if (kcol > qrow + r) s[ni][r] = -1e30f;
        }
      }

      // --- fixed-max exp2 softmax, wave-local P round-trip through LDS ---
      #pragma unroll
      for (int ni = 0; ni < 4; ni++)
        #pragma unroll
        for (int r = 0; r < 4; r++)
          s[ni][r] = exp2f(s[ni][r]);
      #pragma unroll
      for (int r = 0; r < 4; r++)
        lsum[r] += (s[0][r] + s[1][r]) + (s[2][r] + s[3][r]);
      #pragma unroll
      for (int ni = 0; ni < 4; ni++)
        #pragma unroll
        for (int r = 0; r < 4; r++)
          Pls[(w*16 + q_*4 + r) * 76 + ni*16 + m_] = f2bf(s[ni][r]);

      bf16x8 ap[2];
      ap[0] = *(const bf16x8*)&Pls[(w*16 + m_) * 76 + q_*8];
      ap[1] = *(const bf16x8*)&Pls[(w*16 + m_) * 76 + 32 + q_*8];

      // V landed (2 oldest); next-K (2 newest) stays in flight
      if (kt < qt) asm volatile("s_waitcnt vmcnt(2)" ::: "memory");
      else         asm volatile("s_waitcnt vmcnt(0)" ::: "memory");
      __builtin_amdgcn_s_barrier();

      // --- PV from LDS ---
      #pragma unroll
      for (int ni = 0; ni < 4; ni++) {
        const int row = ni*16 + m_;
        const bf16x8 bv0 = *(const bf16x8*)&Vls[row*64 + ((q_     ^ (row & 7)) * 8)];
        const bf16x8 bv1 = *(const bf16x8*)&Vls[row*64 + (((4+q_) ^ (row & 7)) * 8)];
        accO[ni] = mfma16(ap[0], bv0, accO[ni]);
        accO[ni] = mfma16(ap[1], bv1, accO[ni]);
      }

      // next K fully landed + all our LDS reads retired, then handoff barrier
      asm volatile("s_waitcnt vmcnt(0) lgkmcnt(0)" ::: "memory");
      __builtin_amdgcn_s_barrier();
      cur ^= 1;
    }

    // --- epilogue: reduce Sum(p) across the 16 lanes sharing each row, store O/l ---
    #pragma unroll
    for (int r = 0; r < 4; r++) {
      #pragma unroll
      for (int d = 1; d < 16; d <<= 1)
        lsum[r] += __shfl_xor(lsum[r], d, 64);
    }

    const size_t ybase = ((size_t)b * T_ + q0) * C_ + h*64;
    #pragma unroll
    for (int r = 0; r < 4; r++) {
      const int row = w*16 + q_*4 + r;
      const float linv = 1.0f / lsum[r];
      #pragma unroll
      for (int ni = 0; ni < 4; ni++)
        y[ybase + (size_t)row * C_ + ni*16 + m_] = f2bf(accO[ni][r] * linv);
    }
  }
#undef STAGE_K
#undef STAGE_V
}

// ---------------- launch ----------------
extern "C" void kernel_launch(void* const* d_in, const int* in_sizes, int n_in,
                              void* d_out, int out_size, void* d_ws, size_t ws_size,
                              hipStream_t stream) {
  const float* x      = (const float*)d_in[0];
  const float* ln1_g  = (const float*)d_in[1];
  const float* ln1_b  = (const float*)d_in[2];
  const float* w_attn = (const float*)d_in[3];
  const float* b_attn = (const float*)d_in[4];
  const float* w_proj = (const float*)d_in[5];
  const float* b_proj = (const float*)d_in[6];
  const float* ln2_g  = (const float*)d_in[7];
  const float* ln2_b  = (const float*)d_in[8];
  const float* w_fc   = (const float*)d_in[9];
  const float* b_fc   = (const float*)d_in[10];
  const float* w_fc2  = (const float*)d_in[11];
  const float* b_fc2  = (const float*)d_in[12];
  float* out = (float*)d_out;

  char* ws = (char*)d_ws;
  const size_t MB = 1024 * 1024;
  __hip_bfloat16* h      = (__hip_bfloat16*)(ws);                 // 16MB [0,16)
  __hip_bfloat16* qk     = (__hip_bfloat16*)(ws + 16*MB);         // 32MB [16,48)
  __hip_bfloat16* vT     = (__hip_bfloat16*)(ws + 48*MB);         // 16MB [48,64)
  __hip_bfloat16* y      = (__hip_bfloat16*)(ws + 64*MB);         // 16MB [64,80)
  float*          x2     = (float*)        (ws + 80*MB);          // 32MB [80,112)
  __hip_bfloat16* h2     = (__hip_bfloat16*)(ws + 64*MB);         // reuse y slot
  __hip_bfloat16* gbuf   = (__hip_bfloat16*)(ws);                 // 64MB reuse [0,64)
  __hip_bfloat16* wattnT = (__hip_bfloat16*)(ws + 112*MB);        // 6MB
  __hip_bfloat16* wprojT = (__hip_bfloat16*)(ws + 118*MB);        // 2MB
  __hip_bfloat16* wfcT   = (__hip_bfloat16*)(ws + 120*MB);        // 8MB
  __hip_bfloat16* wfc2T  = (__hip_bfloat16*)(ws + 128*MB);        // 8MB

  // weights: [K][N] fp32 -> [N][K] bf16
  transpose_bf16<<<dim3(3*C_/32, C_/32), 256, 0, stream>>>(w_attn, wattnT, C_, 3*C_);
  transpose_bf16<<<dim3(C_/32,  C_/32), 256, 0, stream>>>(w_proj, wprojT, C_, C_);
  transpose_bf16<<<dim3(FF_/32, C_/32), 256, 0, stream>>>(w_fc,   wfcT,   C_, FF_);
  transpose_bf16<<<dim3(C_/32, FF_/32), 256, 0, stream>>>(w_fc2,  wfc2T,  FF_, C_);

  // LN1
  ln_bf16<<<NT_, 256, 0, stream>>>(x, ln1_g, ln1_b, h);
  // QKV: 32m x 12n = 384 blocks; per-XCD chunk 6n x 8m (B-set 3MB L2-resident)
  gemm8p<0><<<dim3(384), 512, 0, stream>>>(h, wattnT, b_attn, nullptr, qk, vT, 3*C_, C_, 6);
  // attention (1024 blocks = 64bh x 16 pairs, 4 blocks/CU, LDS-staged K/V)
  flash_attn<<<dim3(1024), 256, 0, stream>>>(qk, vT, y);
  // proj + residual -> x2 (fp32): 32m x 4n = 128 blocks; chunk 4n x 4m
  gemm8p<1><<<dim3(128), 512, 0, stream>>>(y, wprojT, b_proj, x, x2, nullptr, C_, C_, 4);
  // LN2
  ln_bf16<<<NT_, 256, 0, stream>>>(x2, ln2_g, ln2_b, h2);
  // FC + gelu: 32m x 16n = 512 blocks; chunk 4n x 16m (B-set 2MB)
  gemm8p<2><<<dim3(512), 512, 0, stream>>>(h2, wfcT, b_fc, nullptr, gbuf, nullptr, FF_, C_, 4);
  // FC2 + residual -> out (fp32): 32m x 4n = 128 blocks, K=4096; chunk 1n x 16m
  gemm8p<3><<<dim3(128), 512, 0, stream>>>(gbuf, wfc2T, b_fc2, x2, out, nullptr, C_, FF_, 1);
}